// Round 4
// baseline (384.046 us; speedup 1.0000x reference)
//
#include <hip/hip_runtime.h>
#include <cstddef>

// Problem constants (fixed by reference setup)
constexpr int Bb   = 32;
constexpr int Ss   = 1024;
constexpr int Dd   = 256;
constexpr int Ff   = 256;
constexpr int TMAX = 8192;
constexpr int MM   = Bb * Ss;          // 32768 rows
constexpr int KK   = 768;              // 3*256 reduction dim
constexpr int SP   = 1026;             // padded seq len (zero rows at 0, 1025)
constexpr float LN_EPS = 1e-5f;
constexpr int PIT  = 72;               // LDS pitch (bf16): 144 B rows

typedef __bf16 bf16x8 __attribute__((ext_vector_type(8)));
typedef __bf16 bf16x4 __attribute__((ext_vector_type(4)));
typedef float  f32x4  __attribute__((ext_vector_type(4)));

// ---------------------------------------------------------------------------
// prep_k: three fused prep jobs, split by blockIdx.
//   [0,1536):    pack conv weights [F][D][K] fp32 -> [F][K*256+D] bf16
//   [1536,1568): per-batch cumsum + dur->float + mel_len + searchsorted
//   [1568,1584): zero xp2 pad rows (j=0 and j=1025)
// ---------------------------------------------------------------------------
__global__ __launch_bounds__(256) void prep_k(
    const float* __restrict__ w1, const float* __restrict__ w2,
    __bf16* __restrict__ wTT1, __bf16* __restrict__ wTT2,
    const int* __restrict__ dur, float* __restrict__ dur_out,
    float* __restrict__ mel_out, int* __restrict__ idx,
    __bf16* __restrict__ xp2)
{
    __shared__ int ic[1024];
    __shared__ int sc[256];
    const int blk = blockIdx.x;
    const int tid = threadIdx.x;

    if (blk < 1536) {                       // ---- pack weights ----
        int i = blk * 256 + tid;
        const float* w = w1;
        __bf16* o = wTT1;
        int j = i;
        if (j >= Ff * KK) { j -= Ff * KK; w = w2; o = wTT2; }
        int d  = j & 255;
        int fk = j >> 8;                    // f*3 + k
        int f  = fk / 3;
        int k  = fk - f * 3;
        o[(size_t)f * KK + k * 256 + d] = (__bf16)w[((size_t)(f * 256 + d)) * 3 + k];
        return;
    }
    if (blk >= 1568) {                      // ---- zero xp2 pad rows ----
        int j = (blk - 1568) * 256 + tid;   // 0..4095
        int b = j >> 7;
        int r = (j >> 6) & 1;
        int d = (j & 63) * 4;
        *(bf16x4*)&xp2[((size_t)b * SP + (size_t)r * (SP - 1)) * 256 + d] =
            (bf16x4)(__bf16)0.f;
        return;
    }
    // ---- cumsum + searchsorted for batch b ----
    int b = blk - 1536;
    int4 d4 = ((const int4*)(dur + b * 1024))[tid];
    int l0 = d4.x, l1 = l0 + d4.y, l2 = l1 + d4.z, l3 = l2 + d4.w;
    sc[tid] = l3;
    __syncthreads();
    for (int off = 1; off < 256; off <<= 1) {
        int v = (tid >= off) ? sc[tid - off] : 0;
        __syncthreads();
        sc[tid] += v;
        __syncthreads();
    }
    int excl = sc[tid] - l3;
    ((int4*)ic)[tid] = make_int4(excl + l0, excl + l1, excl + l2, excl + l3);
    ((float4*)(dur_out + b * 1024))[tid] =
        make_float4((float)d4.x, (float)d4.y, (float)d4.z, (float)d4.w);
    if (tid == 255) mel_out[b] = (float)min(excl + l3, TMAX);
    __syncthreads();
    int mel = min(ic[1023], TMAX);
    for (int t = tid; t < TMAX; t += 256) {
        int lo = 0, hi = 1024;
        #pragma unroll
        for (int it = 0; it < 10; ++it) {
            int mid = (lo + hi) >> 1;
            if (ic[mid] <= t) lo = mid + 1; else hi = mid;
        }
        idx[b * TMAX + t] = (t < mel) ? min(lo, 1023) : -1;
    }
}

// ---------------------------------------------------------------------------
// Fused conv-as-GEMM + bias + ReLU + LayerNorm [+ linear head].
// Tile: BM=128 x BN=256 (full F), 512 threads / 8 waves, 64x64 per wave.
// Grid = 256 blocks = 1/CU. BK=64, 12 k-steps.
// MODE 0: A = fp32 x, converted to bf16 in staging (predicated edge rows);
//         writes LN output bf16 into padded xp2.
// MODE 1: A = bf16 padded xp2; writes log_dur fp32.
// ---------------------------------------------------------------------------
template<int MODE>
__global__ __launch_bounds__(512, 1) void gemm_fused(
    const float* __restrict__ Xf,    // MODE 0: [32][1024][256] fp32
    const __bf16* __restrict__ Ap,   // MODE 1: [32][1026][256] bf16 padded
    const __bf16* __restrict__ Bw,   // [256][768]
    const float* __restrict__ bias,
    const float* __restrict__ g, const float* __restrict__ bt,
    const float* __restrict__ lw, const float* __restrict__ lb,
    const unsigned char* __restrict__ mask,
    __bf16* __restrict__ outB, float* __restrict__ outF)
{
    __shared__ __bf16 As[128 * PIT];   // 18432 B
    __shared__ __bf16 Bs[256 * PIT];   // 36864 B

    const int tid  = threadIdx.x;
    const int m0   = blockIdx.x * 128;
    const int bb   = m0 >> 10;
    const int s0   = m0 & 1023;
    const int wave = tid >> 6;         // 0..7
    const int lane = tid & 63;
    const int wm   = (wave & 1) * 64;
    const int wn   = (wave >> 1) * 64;
    const int lm   = lane & 15;
    const int lk   = lane >> 4;

    f32x4 acc[4][4] = {};              // [mi][ni]

    for (int step = 0; step < KK / 64; ++step) {
        const int kk0  = step * 64;
        const int kblk = kk0 >> 8;     // conv tap
        const int d0   = kk0 & 255;

        // ---- stage A: 128 rows x 64 bf16 ----
        if constexpr (MODE == 0) {
            #pragma unroll
            for (int i = 0; i < 4; ++i) {
                int c = i * 512 + tid;          // 0..2047
                int r = c >> 4, q = c & 15;
                int sg = s0 + r + kblk - 1;
                bf16x4 o = (bf16x4)(__bf16)0.f;
                if ((unsigned)sg < 1024u) {
                    float4 v = *(const float4*)&Xf[
                        (((size_t)(bb << 10) + sg) << 8) + d0 + q * 4];
                    o[0] = (__bf16)v.x; o[1] = (__bf16)v.y;
                    o[2] = (__bf16)v.z; o[3] = (__bf16)v.w;
                }
                *(bf16x4*)&As[r * PIT + q * 4] = o;
            }
        } else {
            const __bf16* aSrc = Ap + (((size_t)(bb * SP + s0 + kblk)) << 8) + d0;
            #pragma unroll
            for (int i = 0; i < 2; ++i) {
                int c = i * 512 + tid;          // 0..1023
                int r = c >> 3, q = c & 7;
                *(bf16x8*)&As[r * PIT + q * 8] =
                    *(const bf16x8*)&aSrc[((size_t)r << 8) + q * 8];
            }
        }
        // ---- stage B: 256 rows x 64 bf16 ----
        const __bf16* bSrc = Bw + kk0;
        #pragma unroll
        for (int i = 0; i < 4; ++i) {
            int c = i * 512 + tid;              // 0..2047
            int r = c >> 3, q = c & 7;
            *(bf16x8*)&Bs[r * PIT + q * 8] =
                *(const bf16x8*)&bSrc[(size_t)r * KK + q * 8];
        }
        __syncthreads();

        #pragma unroll
        for (int kc = 0; kc < 2; ++kc) {
            bf16x8 af[4], bfr[4];
            #pragma unroll
            for (int mi = 0; mi < 4; ++mi)
                af[mi] = *(const bf16x8*)&As[(wm + mi * 16 + lm) * PIT + kc * 32 + lk * 8];
            #pragma unroll
            for (int ni = 0; ni < 4; ++ni)
                bfr[ni] = *(const bf16x8*)&Bs[(wn + ni * 16 + lm) * PIT + kc * 32 + lk * 8];
            #pragma unroll
            for (int mi = 0; mi < 4; ++mi)
                #pragma unroll
                for (int ni = 0; ni < 4; ++ni)
                    acc[mi][ni] = __builtin_amdgcn_mfma_f32_16x16x32_bf16(
                        af[mi], bfr[ni], acc[mi][ni], 0, 0, 0);
        }
        __syncthreads();
    }

    // ---- epilogue: bias + ReLU, LN row stats across 4 col-waves ----
    // C/D layout: col = wn + ni*16 + lm, row = wm + mi*16 + lk*4 + r
    float* scrS = (float*)As;          // [8 waves][64 row-slots]
    float* scrQ = scrS + 512;

    float s_[4][4] = {}, q_[4][4] = {};
    #pragma unroll
    for (int ni = 0; ni < 4; ++ni) {
        float bv = bias[wn + ni * 16 + lm];
        #pragma unroll
        for (int mi = 0; mi < 4; ++mi)
            #pragma unroll
            for (int r = 0; r < 4; ++r) {
                float h = fmaxf(acc[mi][ni][r] + bv, 0.f);
                acc[mi][ni][r] = h;
                s_[mi][r] += h;
                q_[mi][r] += h * h;
            }
    }
    #pragma unroll
    for (int off = 1; off < 16; off <<= 1)
        #pragma unroll
        for (int mi = 0; mi < 4; ++mi)
            #pragma unroll
            for (int r = 0; r < 4; ++r) {
                s_[mi][r] += __shfl_xor(s_[mi][r], off, 64);
                q_[mi][r] += __shfl_xor(q_[mi][r], off, 64);
            }
    if (lm == 0) {
        #pragma unroll
        for (int mi = 0; mi < 4; ++mi)
            #pragma unroll
            for (int r = 0; r < 4; ++r) {
                int rl = mi * 16 + lk * 4 + r;      // 0..63 within wm-half
                scrS[wave * 64 + rl] = s_[mi][r];
                scrQ[wave * 64 + rl] = q_[mi][r];
            }
    }
    __syncthreads();

    const int half = wave & 1;                      // which wm-half this wave owns
    float mu[4][4], rs[4][4];
    #pragma unroll
    for (int mi = 0; mi < 4; ++mi)
        #pragma unroll
        for (int r = 0; r < 4; ++r) {
            int rl = mi * 16 + lk * 4 + r;
            float S = scrS[(0 + half) * 64 + rl] + scrS[(2 + half) * 64 + rl]
                    + scrS[(4 + half) * 64 + rl] + scrS[(6 + half) * 64 + rl];
            float Q = scrQ[(0 + half) * 64 + rl] + scrQ[(2 + half) * 64 + rl]
                    + scrQ[(4 + half) * 64 + rl] + scrQ[(6 + half) * 64 + rl];
            float m_ = S * (1.f / 256.f);
            float v_ = Q * (1.f / 256.f) - m_ * m_;
            mu[mi][r] = m_;
            rs[mi][r] = rsqrtf(v_ + LN_EPS);
        }

    if constexpr (MODE == 0) {
        size_t obase = ((size_t)(bb * SP + s0 + 1 + wm)) << 8;
        #pragma unroll
        for (int ni = 0; ni < 4; ++ni) {
            int col = wn + ni * 16 + lm;
            float gv = g[col], bv2 = bt[col];
            #pragma unroll
            for (int mi = 0; mi < 4; ++mi)
                #pragma unroll
                for (int r = 0; r < 4; ++r) {
                    int rl = mi * 16 + lk * 4 + r;
                    float o = (acc[mi][ni][r] - mu[mi][r]) * rs[mi][r] * gv + bv2;
                    outB[obase + ((size_t)rl << 8) + col] = (__bf16)o;
                }
        }
    } else {
        float p_[4][4] = {};
        #pragma unroll
        for (int ni = 0; ni < 4; ++ni) {
            int col = wn + ni * 16 + lm;
            float gv = g[col], bv2 = bt[col], wv = lw[col];
            #pragma unroll
            for (int mi = 0; mi < 4; ++mi)
                #pragma unroll
                for (int r = 0; r < 4; ++r) {
                    float o = (acc[mi][ni][r] - mu[mi][r]) * rs[mi][r] * gv + bv2;
                    p_[mi][r] += o * wv;
                }
        }
        #pragma unroll
        for (int off = 1; off < 16; off <<= 1)
            #pragma unroll
            for (int mi = 0; mi < 4; ++mi)
                #pragma unroll
                for (int r = 0; r < 4; ++r)
                    p_[mi][r] += __shfl_xor(p_[mi][r], off, 64);
        __syncthreads();                   // done reading scrS/scrQ
        if (lm == 0) {
            #pragma unroll
            for (int mi = 0; mi < 4; ++mi)
                #pragma unroll
                for (int r = 0; r < 4; ++r)
                    scrS[wave * 64 + (mi * 16 + lk * 4 + r)] = p_[mi][r];
        }
        __syncthreads();
        if (tid < 128) {
            int gr = tid;                  // 0..127
            int h = gr >> 6, rl = gr & 63;
            float v = scrS[(0 + h) * 64 + rl] + scrS[(2 + h) * 64 + rl]
                    + scrS[(4 + h) * 64 + rl] + scrS[(6 + h) * 64 + rl] + lb[0];
            if (mask[m0 + gr]) v = 0.f;
            outF[m0 + gr] = v;
        }
    }
}

// ---------------------------------------------------------------------------
// Gather rows of x per src idx; zero invalid rows. float4 granularity.
// ---------------------------------------------------------------------------
__global__ __launch_bounds__(256) void gather_k(
    const float4* __restrict__ xv, const int* __restrict__ idx,
    float4* __restrict__ outv)
{
    int g   = blockIdx.x * 256 + threadIdx.x;
    int row = g >> 6;                           // b*T + t
    int col = g & 63;
    int s = idx[row];
    float4 v = make_float4(0.f, 0.f, 0.f, 0.f);
    if (s >= 0) {
        int b = row >> 13;
        v = xv[((size_t)(b << 10) + s) * 64 + col];
    }
    outv[g] = v;
}

// ---------------------------------------------------------------------------
extern "C" void kernel_launch(void* const* d_in, const int* in_sizes, int n_in,
                              void* d_out, int out_size, void* d_ws, size_t ws_size,
                              hipStream_t stream)
{
    const float* x            = (const float*)d_in[0];
    const unsigned char* mask = (const unsigned char*)d_in[1];
    const int* duration       = (const int*)d_in[2];
    const float* w1  = (const float*)d_in[4];
    const float* b1  = (const float*)d_in[5];
    const float* g1  = (const float*)d_in[6];
    const float* be1 = (const float*)d_in[7];
    const float* w2  = (const float*)d_in[8];
    const float* b2  = (const float*)d_in[9];
    const float* g2  = (const float*)d_in[10];
    const float* be2 = (const float*)d_in[11];
    const float* lw  = (const float*)d_in[12];
    const float* lb  = (const float*)d_in[13];

    float* out        = (float*)d_out;
    float* out0       = out;                                  // [B,T,D]
    float* out_logdur = out + (size_t)Bb * TMAX * Dd;         // [B,S]
    float* out_dur    = out_logdur + (size_t)Bb * Ss;         // [B,S]
    float* out_mel    = out_dur + (size_t)Bb * Ss;            // [B]

    char* ws = (char*)d_ws;
    __bf16* xp2  = (__bf16*)ws;                               // 32*1026*256
    __bf16* wTT1 = xp2 + (size_t)Bb * SP * 256;               // 256*768
    __bf16* wTT2 = wTT1 + (size_t)Ff * KK;
    int*    idx  = (int*)(wTT2 + (size_t)Ff * KK);            // 32*8192

    prep_k<<<1584, 256, 0, stream>>>(w1, w2, wTT1, wTT2,
                                     duration, out_dur, out_mel, idx, xp2);
    gemm_fused<0><<<MM / 128, 512, 0, stream>>>(
        x, nullptr, wTT1, b1, g1, be1, nullptr, nullptr, nullptr, xp2, nullptr);
    gemm_fused<1><<<MM / 128, 512, 0, stream>>>(
        nullptr, xp2, wTT2, b2, g2, be2, lw, lb, mask, nullptr, out_logdur);
    gather_k<<<(Bb * TMAX * Dd / 4) / 256, 256, 0, stream>>>(
        (const float4*)x, idx, (float4*)out0);
}